// Round 2
// baseline (107.066 us; speedup 1.0000x reference)
//
#include <hip/hip_runtime.h>

// LDDMM variational evolve: B=1, N=8192, D=3, fp32.
// dmom_i = 2g * (x_i * sum_j w_ij  -  sum_j w_ij x_j),  w_ij = K_ij <p_i,p_j>
// dx_i   = sum_j K_ij p_j,   K_ij = exp(-g |x_i - x_j|^2), g = 100.
//
// Round 2: no atomics (ws partials + reduce + finalize), pre-scaled LDS tiles
// (exponent = 1 add + 3 fma + v_exp_f32), float4 LDS reads, 2048-block grid.

#define TPB 256
constexpr float GAMMA_C = 100.0f;
constexpr float LOG2E_C = 1.4426950408889634f;
constexpr float SB_C    = 2.0f * GAMMA_C * LOG2E_C;  // b' = SB*x_j
constexpr float SC_C    = -GAMMA_C * LOG2E_C;        // c  = SC*|x|^2
constexpr float LN2_C   = 0.69314718055994531f;      // 2g/SB

// ---- Kernel A: per-segment partial sums ------------------------------------
// grid (N/TPB, SEG). Block (bx,seg): i in [bx*TPB, ...), j in [seg*JT, ...).
// ws layout: P[c][s][i], c=0..6 (a, wx', wy', wz', gx, gy, gz), each [SEG][N].
__global__ __launch_bounds__(TPB, 8) void lddmm_partial(
    const float* __restrict__ mom, const float* __restrict__ xpt,
    float* __restrict__ ws, int N, int SEG, int JT) {
  extern __shared__ float4 smem[];
  float4* sA = smem;        // {SB*x, SB*y, SB*z, SC*|x|^2}
  float4* sP = smem + JT;   // {px, py, pz, 0}
  const int tid = threadIdx.x;
  const int seg = blockIdx.y;

  for (int t = tid; t < JT; t += TPB) {
    const int j = seg * JT + t;
    const float bx = xpt[3*j], by = xpt[3*j+1], bz = xpt[3*j+2];
    sA[t] = make_float4(SB_C*bx, SB_C*by, SB_C*bz,
                        SC_C * fmaf(bx, bx, fmaf(by, by, bz*bz)));
    sP[t] = make_float4(mom[3*j], mom[3*j+1], mom[3*j+2], 0.f);
  }
  __syncthreads();

  const int i = blockIdx.x * TPB + tid;
  const float xi  = xpt[3*i], yi  = xpt[3*i+1], zi  = xpt[3*i+2];
  const float pxi = mom[3*i], pyi = mom[3*i+1], pzi = mom[3*i+2];
  const float ci  = SC_C * fmaf(xi, xi, fmaf(yi, yi, zi*zi));

  float a = 0.f;                          // sum w
  float wx = 0.f, wy = 0.f, wz = 0.f;     // sum w * (SB*x_j)
  float gx = 0.f, gy = 0.f, gz = 0.f;     // sum K * p_j

#pragma unroll 4
  for (int t = 0; t < JT; ++t) {
    const float4 A = sA[t];
    const float4 P = sP[t];
    // arg = log2e * (-g |xi - xj|^2) = ci + cj + <SB*xj, xi>
    const float arg = fmaf(A.x, xi, fmaf(A.y, yi, fmaf(A.z, zi, ci + A.w)));
    const float K   = exp2f(arg);                       // v_exp_f32
    const float dot = fmaf(P.x, pxi, fmaf(P.y, pyi, P.z * pzi));
    const float w   = K * dot;
    a  += w;
    wx = fmaf(w, A.x, wx); wy = fmaf(w, A.y, wy); wz = fmaf(w, A.z, wz);
    gx = fmaf(K, P.x, gx); gy = fmaf(K, P.y, gy); gz = fmaf(K, P.z, gz);
  }

  const size_t SN = (size_t)SEG * N;
  float* p = ws + (size_t)seg * N + i;
  p[0*SN] = a;
  p[1*SN] = wx; p[2*SN] = wy; p[3*SN] = wz;
  p[4*SN] = gx; p[5*SN] = gy; p[6*SN] = gz;
}

// ---- Kernel B: reduce over segments ----------------------------------------
// grid (N/TPB, 7): component c = blockIdx.y. R[c][i] = sum_s P[c][s][i].
__global__ __launch_bounds__(TPB) void lddmm_reduce(
    const float* __restrict__ ws, float* __restrict__ R, int N, int SEG) {
  const int i = blockIdx.x * TPB + threadIdx.x;
  const int c = blockIdx.y;
  const float* src = ws + (size_t)c * SEG * N + i;
  float s0 = 0.f, s1 = 0.f, s2 = 0.f, s3 = 0.f;
  int s = 0;
  for (; s + 4 <= SEG; s += 4) {
    s0 += src[(size_t)(s+0)*N]; s1 += src[(size_t)(s+1)*N];
    s2 += src[(size_t)(s+2)*N]; s3 += src[(size_t)(s+3)*N];
  }
  for (; s < SEG; ++s) s0 += src[(size_t)s*N];
  R[(size_t)c * N + i] = (s0 + s1) + (s2 + s3);
}

// ---- Kernel C: finalize ----------------------------------------------------
// dmom_x = 2g*xi*A - ln2*WX'   (WX' accumulated against SB*x_j; 2g/SB = ln2)
__global__ __launch_bounds__(TPB) void lddmm_finalize(
    const float* __restrict__ R, const float* __restrict__ xpt,
    float* __restrict__ out, int N) {
  const int i = blockIdx.x * TPB + threadIdx.x;
  const float A  = R[i];
  const float WX = R[(size_t)1*N+i], WY = R[(size_t)2*N+i], WZ = R[(size_t)3*N+i];
  const float GX = R[(size_t)4*N+i], GY = R[(size_t)5*N+i], GZ = R[(size_t)6*N+i];
  const float xi = xpt[3*i], yi = xpt[3*i+1], zi = xpt[3*i+2];
  const float TGA = 2.0f * GAMMA_C * A;
  out[3*i+0] = fmaf(TGA, xi, -LN2_C * WX);
  out[3*i+1] = fmaf(TGA, yi, -LN2_C * WY);
  out[3*i+2] = fmaf(TGA, zi, -LN2_C * WZ);
  out[3*N + 3*i + 0] = GX;
  out[3*N + 3*i + 1] = GY;
  out[3*N + 3*i + 2] = GZ;
}

// ---- Fallback (tiny ws): round-1 atomic version ----------------------------
__global__ __launch_bounds__(TPB) void lddmm_atomic(
    const float* __restrict__ mom, const float* __restrict__ xpt,
    float* __restrict__ out, int N) {
  const int i  = blockIdx.x * TPB + threadIdx.x;
  const int jb = blockIdx.y * TPB;
  __shared__ float4 sA[TPB], sP[TPB];
  {
    const int j = jb + threadIdx.x;
    const float bx = xpt[3*j], by = xpt[3*j+1], bz = xpt[3*j+2];
    sA[threadIdx.x] = make_float4(SB_C*bx, SB_C*by, SB_C*bz,
                                  SC_C * fmaf(bx, bx, fmaf(by, by, bz*bz)));
    sP[threadIdx.x] = make_float4(mom[3*j], mom[3*j+1], mom[3*j+2], 0.f);
  }
  __syncthreads();
  const float xi = xpt[3*i], yi = xpt[3*i+1], zi = xpt[3*i+2];
  const float pxi = mom[3*i], pyi = mom[3*i+1], pzi = mom[3*i+2];
  const float ci = SC_C * fmaf(xi, xi, fmaf(yi, yi, zi*zi));
  float a=0.f, wx=0.f, wy=0.f, wz=0.f, gx=0.f, gy=0.f, gz=0.f;
#pragma unroll 4
  for (int t = 0; t < TPB; ++t) {
    const float4 A = sA[t], P = sP[t];
    const float arg = fmaf(A.x, xi, fmaf(A.y, yi, fmaf(A.z, zi, ci + A.w)));
    const float K   = exp2f(arg);
    const float dot = fmaf(P.x, pxi, fmaf(P.y, pyi, P.z * pzi));
    const float w   = K * dot;
    a += w;
    wx = fmaf(w, A.x, wx); wy = fmaf(w, A.y, wy); wz = fmaf(w, A.z, wz);
    gx = fmaf(K, P.x, gx); gy = fmaf(K, P.y, gy); gz = fmaf(K, P.z, gz);
  }
  const float TGA = 2.0f * GAMMA_C * a;
  atomicAdd(&out[3*i+0], fmaf(TGA, xi, -LN2_C * wx));
  atomicAdd(&out[3*i+1], fmaf(TGA, yi, -LN2_C * wy));
  atomicAdd(&out[3*i+2], fmaf(TGA, zi, -LN2_C * wz));
  atomicAdd(&out[3*N+3*i+0], gx);
  atomicAdd(&out[3*N+3*i+1], gy);
  atomicAdd(&out[3*N+3*i+2], gz);
}

extern "C" void kernel_launch(void* const* d_in, const int* in_sizes, int n_in,
                              void* d_out, int out_size, void* d_ws, size_t ws_size,
                              hipStream_t stream) {
  const float* mom = (const float*)d_in[0];   // setup_inputs order: mom first
  const float* xpt = (const float*)d_in[1];   // control_points second
  float* out = (float*)d_out;
  const int N = in_sizes[0] / 3;              // 8192

  auto need = [&](int s) { return (size_t)(7*s + 7) * (size_t)N * sizeof(float); };
  int SEG = 64;                               // 2048 blocks = 8 blocks/CU
  while (SEG > 2 && need(SEG) > ws_size) SEG >>= 1;

  if (need(SEG) <= ws_size) {
    const int JT = N / SEG;                   // j-tile per block (128 @ SEG=64)
    float* wsf = (float*)d_ws;
    float* R   = wsf + (size_t)7 * SEG * N;
    const size_t shmem = (size_t)JT * 2 * sizeof(float4);
    dim3 gA(N / TPB, SEG);
    lddmm_partial<<<gA, TPB, shmem, stream>>>(mom, xpt, wsf, N, SEG, JT);
    dim3 gB(N / TPB, 7);
    lddmm_reduce<<<gB, TPB, 0, stream>>>(wsf, R, N, SEG);
    lddmm_finalize<<<N / TPB, TPB, 0, stream>>>(R, xpt, out, N);
  } else {
    // ws too small — atomic fallback (d_out poisoned every call, so zero it)
    hipMemsetAsync(d_out, 0, (size_t)out_size * sizeof(float), stream);
    dim3 grid(N / TPB, N / TPB);
    lddmm_atomic<<<grid, TPB, 0, stream>>>(mom, xpt, out, N);
  }
}

// Round 3
// 97.041 us; speedup vs baseline: 1.1033x; 1.1033x over previous
//
#include <hip/hip_runtime.h>

// LDDMM variational evolve: B=1, N=8192, D=3, fp32.
// dmom_i = 2g * (x_i * sum_j w_ij  -  sum_j w_ij x_j),  w_ij = K_ij <p_i,p_j>
// dx_i   = sum_j K_ij p_j,   K_ij = exp(-g |x_i - x_j|^2), g = 100.
//
// Round 3: raw v_exp_f32 (__builtin_amdgcn_exp2f) instead of OCML exp2f
// (rocprof showed ~44 VALU instr/iter: the OCML slow path was ~28 of them),
// plus 2-way i register tiling to amortize LDS reads and hide lgkm stalls.
// NOTE: ci must stay inside the exponent (arg <= 0 always); factoring
// exp2(ci) out overflows: inner arg reaches +432 -> inf * 0 = NaN.

#define TPB 256
#define ITILE 2
constexpr float GAMMA_C = 100.0f;
constexpr float LOG2E_C = 1.4426950408889634f;
constexpr float SB_C    = 2.0f * GAMMA_C * LOG2E_C;  // A.xyz = SB*x_j
constexpr float SC_C    = -GAMMA_C * LOG2E_C;        // A.w   = SC*|x_j|^2
constexpr float LN2_C   = 0.69314718055994531f;      // 2g/SB

// ---- Kernel A: per-segment partial sums ------------------------------------
// grid (N/(TPB*ITILE), SEG). ws layout: P[c][s][i], c=0..6, each [SEG][N].
__global__ __launch_bounds__(TPB, 4) void lddmm_partial(
    const float* __restrict__ mom, const float* __restrict__ xpt,
    float* __restrict__ ws, int N, int SEG, int JT) {
  extern __shared__ float4 smem[];
  float4* sA = smem;        // {SB*x, SB*y, SB*z, SC*|x|^2}
  float4* sP = smem + JT;   // {px, py, pz, 0}
  const int tid = threadIdx.x;
  const int seg = blockIdx.y;

  for (int t = tid; t < JT; t += TPB) {
    const int j = seg * JT + t;
    const float bx = xpt[3*j], by = xpt[3*j+1], bz = xpt[3*j+2];
    sA[t] = make_float4(SB_C*bx, SB_C*by, SB_C*bz,
                        SC_C * fmaf(bx, bx, fmaf(by, by, bz*bz)));
    sP[t] = make_float4(mom[3*j], mom[3*j+1], mom[3*j+2], 0.f);
  }
  __syncthreads();

  const int i0 = blockIdx.x * (TPB * ITILE) + tid;
  const int i1 = i0 + TPB;

  const float x0 = xpt[3*i0], y0 = xpt[3*i0+1], z0 = xpt[3*i0+2];
  const float p0x = mom[3*i0], p0y = mom[3*i0+1], p0z = mom[3*i0+2];
  const float c0 = SC_C * fmaf(x0, x0, fmaf(y0, y0, z0*z0));
  const float x1 = xpt[3*i1], y1 = xpt[3*i1+1], z1 = xpt[3*i1+2];
  const float p1x = mom[3*i1], p1y = mom[3*i1+1], p1z = mom[3*i1+2];
  const float c1 = SC_C * fmaf(x1, x1, fmaf(y1, y1, z1*z1));

  float a0=0.f, wx0=0.f, wy0=0.f, wz0=0.f, gx0=0.f, gy0=0.f, gz0=0.f;
  float a1=0.f, wx1=0.f, wy1=0.f, wz1=0.f, gx1=0.f, gy1=0.f, gz1=0.f;

#pragma unroll 4
  for (int t = 0; t < JT; ++t) {
    const float4 A = sA[t];
    const float4 P = sP[t];
    // i0
    {
      const float arg = fmaf(A.x, x0, fmaf(A.y, y0, fmaf(A.z, z0, c0 + A.w)));
      const float K   = __builtin_amdgcn_exp2f(arg);          // bare v_exp_f32
      const float dot = fmaf(P.x, p0x, fmaf(P.y, p0y, P.z * p0z));
      const float w   = K * dot;
      a0 += w;
      wx0 = fmaf(w, A.x, wx0); wy0 = fmaf(w, A.y, wy0); wz0 = fmaf(w, A.z, wz0);
      gx0 = fmaf(K, P.x, gx0); gy0 = fmaf(K, P.y, gy0); gz0 = fmaf(K, P.z, gz0);
    }
    // i1
    {
      const float arg = fmaf(A.x, x1, fmaf(A.y, y1, fmaf(A.z, z1, c1 + A.w)));
      const float K   = __builtin_amdgcn_exp2f(arg);
      const float dot = fmaf(P.x, p1x, fmaf(P.y, p1y, P.z * p1z));
      const float w   = K * dot;
      a1 += w;
      wx1 = fmaf(w, A.x, wx1); wy1 = fmaf(w, A.y, wy1); wz1 = fmaf(w, A.z, wz1);
      gx1 = fmaf(K, P.x, gx1); gy1 = fmaf(K, P.y, gy1); gz1 = fmaf(K, P.z, gz1);
    }
  }

  const size_t SN = (size_t)SEG * N;
  float* p = ws + (size_t)seg * N;
  p[0*SN+i0] = a0;  p[0*SN+i1] = a1;
  p[1*SN+i0] = wx0; p[1*SN+i1] = wx1;
  p[2*SN+i0] = wy0; p[2*SN+i1] = wy1;
  p[3*SN+i0] = wz0; p[3*SN+i1] = wz1;
  p[4*SN+i0] = gx0; p[4*SN+i1] = gx1;
  p[5*SN+i0] = gy0; p[5*SN+i1] = gy1;
  p[6*SN+i0] = gz0; p[6*SN+i1] = gz1;
}

// ---- Kernel B: reduce over segments ----------------------------------------
__global__ __launch_bounds__(TPB) void lddmm_reduce(
    const float* __restrict__ ws, float* __restrict__ R, int N, int SEG) {
  const int i = blockIdx.x * TPB + threadIdx.x;
  const int c = blockIdx.y;
  const float* src = ws + (size_t)c * SEG * N + i;
  float s0 = 0.f, s1 = 0.f, s2 = 0.f, s3 = 0.f;
  int s = 0;
  for (; s + 4 <= SEG; s += 4) {
    s0 += src[(size_t)(s+0)*N]; s1 += src[(size_t)(s+1)*N];
    s2 += src[(size_t)(s+2)*N]; s3 += src[(size_t)(s+3)*N];
  }
  for (; s < SEG; ++s) s0 += src[(size_t)s*N];
  R[(size_t)c * N + i] = (s0 + s1) + (s2 + s3);
}

// ---- Kernel C: finalize ----------------------------------------------------
__global__ __launch_bounds__(TPB) void lddmm_finalize(
    const float* __restrict__ R, const float* __restrict__ xpt,
    float* __restrict__ out, int N) {
  const int i = blockIdx.x * TPB + threadIdx.x;
  const float A  = R[i];
  const float WX = R[(size_t)1*N+i], WY = R[(size_t)2*N+i], WZ = R[(size_t)3*N+i];
  const float GX = R[(size_t)4*N+i], GY = R[(size_t)5*N+i], GZ = R[(size_t)6*N+i];
  const float xi = xpt[3*i], yi = xpt[3*i+1], zi = xpt[3*i+2];
  const float TGA = 2.0f * GAMMA_C * A;
  out[3*i+0] = fmaf(TGA, xi, -LN2_C * WX);
  out[3*i+1] = fmaf(TGA, yi, -LN2_C * WY);
  out[3*i+2] = fmaf(TGA, zi, -LN2_C * WZ);
  out[3*N + 3*i + 0] = GX;
  out[3*N + 3*i + 1] = GY;
  out[3*N + 3*i + 2] = GZ;
}

// ---- Fallback (tiny ws): atomic single-kernel version ----------------------
__global__ __launch_bounds__(TPB) void lddmm_atomic(
    const float* __restrict__ mom, const float* __restrict__ xpt,
    float* __restrict__ out, int N) {
  const int i  = blockIdx.x * TPB + threadIdx.x;
  const int jb = blockIdx.y * TPB;
  __shared__ float4 sA[TPB], sP[TPB];
  {
    const int j = jb + threadIdx.x;
    const float bx = xpt[3*j], by = xpt[3*j+1], bz = xpt[3*j+2];
    sA[threadIdx.x] = make_float4(SB_C*bx, SB_C*by, SB_C*bz,
                                  SC_C * fmaf(bx, bx, fmaf(by, by, bz*bz)));
    sP[threadIdx.x] = make_float4(mom[3*j], mom[3*j+1], mom[3*j+2], 0.f);
  }
  __syncthreads();
  const float xi = xpt[3*i], yi = xpt[3*i+1], zi = xpt[3*i+2];
  const float pxi = mom[3*i], pyi = mom[3*i+1], pzi = mom[3*i+2];
  const float ci = SC_C * fmaf(xi, xi, fmaf(yi, yi, zi*zi));
  float a=0.f, wx=0.f, wy=0.f, wz=0.f, gx=0.f, gy=0.f, gz=0.f;
#pragma unroll 4
  for (int t = 0; t < TPB; ++t) {
    const float4 A = sA[t], P = sP[t];
    const float arg = fmaf(A.x, xi, fmaf(A.y, yi, fmaf(A.z, zi, ci + A.w)));
    const float K   = __builtin_amdgcn_exp2f(arg);
    const float dot = fmaf(P.x, pxi, fmaf(P.y, pyi, P.z * pzi));
    const float w   = K * dot;
    a += w;
    wx = fmaf(w, A.x, wx); wy = fmaf(w, A.y, wy); wz = fmaf(w, A.z, wz);
    gx = fmaf(K, P.x, gx); gy = fmaf(K, P.y, gy); gz = fmaf(K, P.z, gz);
  }
  const float TGA = 2.0f * GAMMA_C * a;
  atomicAdd(&out[3*i+0], fmaf(TGA, xi, -LN2_C * wx));
  atomicAdd(&out[3*i+1], fmaf(TGA, yi, -LN2_C * wy));
  atomicAdd(&out[3*i+2], fmaf(TGA, zi, -LN2_C * wz));
  atomicAdd(&out[3*N+3*i+0], gx);
  atomicAdd(&out[3*N+3*i+1], gy);
  atomicAdd(&out[3*N+3*i+2], gz);
}

extern "C" void kernel_launch(void* const* d_in, const int* in_sizes, int n_in,
                              void* d_out, int out_size, void* d_ws, size_t ws_size,
                              hipStream_t stream) {
  const float* mom = (const float*)d_in[0];   // setup_inputs order: mom first
  const float* xpt = (const float*)d_in[1];   // control_points second
  float* out = (float*)d_out;
  const int N = in_sizes[0] / 3;              // 8192

  auto need = [&](int s) { return (size_t)(7*s + 7) * (size_t)N * sizeof(float); };
  int SEG = 64;
  while (SEG > 2 && need(SEG) > ws_size) SEG >>= 1;

  if (need(SEG) <= ws_size) {
    const int JT = N / SEG;                   // 128 @ SEG=64
    float* wsf = (float*)d_ws;
    float* R   = wsf + (size_t)7 * SEG * N;
    const size_t shmem = (size_t)JT * 2 * sizeof(float4);
    dim3 gA(N / (TPB * ITILE), SEG);          // (16, 64) = 1024 blocks
    lddmm_partial<<<gA, TPB, shmem, stream>>>(mom, xpt, wsf, N, SEG, JT);
    dim3 gB(N / TPB, 7);
    lddmm_reduce<<<gB, TPB, 0, stream>>>(wsf, R, N, SEG);
    lddmm_finalize<<<N / TPB, TPB, 0, stream>>>(R, xpt, out, N);
  } else {
    hipMemsetAsync(d_out, 0, (size_t)out_size * sizeof(float), stream);
    dim3 grid(N / TPB, N / TPB);
    lddmm_atomic<<<grid, TPB, 0, stream>>>(mom, xpt, out, N);
  }
}